// Round 9
// baseline (177.137 us; speedup 1.0000x reference)
//
#include <hip/hip_runtime.h>
#include <stdint.h>

#define NCLS 80
#define MAXB 150
#define BATCH 16
#define NANCH 25200
#define CAP 2048     // per-(image,class) candidate cap; mean fill ~600 -> >40 sigma
#define CAP2 12000   // hard bound: 80 classes * 150 kept max
#define NBINS 411    // score hi-bits (0x3F666666,0x3F800000] -> bins 0..410
#define SELCAP 2048
#define NSEL 1024    // nms histogram-compact capacity (expected ~155)
#define NREC_ALL 403200  // total records across levels/images
#define NF4_L0 408000u   // 16*1200*85/4
#define NF4_L01 2040000u // + 16*4800*85/4
#define NF4_ALL 8568000u // + 16*19200*85/4
#define CPAD 16          // counters padded to one per 64B line (atomic contention fix)
#define SCAN_PER 8       // float4s per thread in scan (MLP)

typedef unsigned long long u64;
typedef unsigned int u32;
typedef float f4 __attribute__((ext_vector_type(4)));
typedef f4 f4u __attribute__((aligned(4)));  // 4B-aligned vector load

__device__ __forceinline__ float sigm(float x) { return 1.0f / (1.0f + expf(-x)); }

// ---------------- Pass 1a: headers -> boxes + cs + thr (thread per record) ------
__global__ __launch_bounds__(256) void header_kernel(
    const float* __restrict__ p0, const float* __restrict__ p1,
    const float* __restrict__ p2, float* __restrict__ boxes_ws,
    float* __restrict__ cs_arr, float* __restrict__ thr_arr) {
  int W = blockIdx.x * 256 + threadIdx.x;  // 0..403199, level-major record id
  int lvl, b, r;
  if (W < 19200) { lvl = 0; b = W / 1200; r = W - b * 1200; }
  else if (W < 96000) { int V = W - 19200; lvl = 1; b = V / 4800; r = V - b * 4800; }
  else { int V = W - 96000; lvl = 2; b = V / 19200; r = V - b * 19200; }
  const int gtab[3] = {20, 40, 80};
  const float rtab[3] = {32.f, 16.f, 8.f};
  const int nbt[3] = {0, 1200, 6000};
  const float awt[3][3] = {{116.f, 156.f, 373.f}, {30.f, 62.f, 59.f}, {10.f, 16.f, 33.f}};
  const float aht[3][3] = {{90.f, 198.f, 326.f}, {61.f, 45.f, 119.f}, {13.f, 30.f, 23.f}};
  const float* fm = (lvl == 0) ? p0 : ((lvl == 1) ? p1 : p2);
  int g = gtab[lvl];
  const float* p = fm + ((size_t)b * (g * g * 3) + r) * 85;
  f4 h = *(const f4u*)p;   // tx,ty,tw,th (4B-aligned vector load)
  float tc = p[4];
  int cell = r / 3, a = r - 3 * cell;
  int yy = cell / g, xx = cell - yy * g;
  float ratio = rtab[lvl];
  float cx = (sigm(h.x) + (float)xx) * ratio;
  float cy = (sigm(h.y) + (float)yy) * ratio;
  float w = expf(h.z) * awt[lvl][a];
  float hh = expf(h.w) * aht[lvl][a];
  int n = nbt[lvl] + r;
  reinterpret_cast<float4*>(boxes_ws)[(size_t)b * NANCH + n] = make_float4(
      cx - w * 0.5f, cy - hh * 0.5f, cx + w * 0.5f, cy + hh * 0.5f);
  float cs = sigm(tc);  // score<=cs in fp32 -> cs>0.9 is a lossless gate
  cs_arr[W] = cs;
  // conservative logit threshold: val <= thr  ==>  fl(cs*sigm(val)) <= 0.9f.
  // margin 1e-3 + 4e-7*ratio dominates all fp32 error terms (sigm chain
  // ~4e-7/(1-t), div/log ulps); false-positives are re-tested exactly in scan.
  float thr = __int_as_float(0x7F800000);  // +INF: cs<=0.9 -> s<=cs<=0.9, no hit
  float t = 0.9f / cs;
  if (t < 1.0f) {
    float ratio2 = t / (1.0f - t);
    thr = logf(ratio2) - (1e-3f + 4e-7f * ratio2);
  }
  thr_arr[W] = thr;
}

// ---------------- Pass 1b: streaming class scan (SCAN_PER float4s / thread) -----
template <int NREC, int NBT, int CSB>
__device__ __forceinline__ void scan4(f4 v, u32 e,
                                      const float* __restrict__ thr_arr,
                                      const float* __restrict__ cs_arr,
                                      u64* __restrict__ ck, int* __restrict__ cc) {
  u32 R0 = e / 85u;          // one div per float4 (amortized)
  u32 o0 = e - R0 * 85u;
  float t0 = thr_arr[CSB + R0];
  float t1 = thr_arr[CSB + R0 + 1];  // pad entry exists; only read, selected iff roll
  bool cand[4], roll[4];
  bool any = false;
#pragma unroll
  for (int k = 0; k < 4; ++k) {
    u32 o = o0 + (u32)k;
    bool rl = o >= 85u;
    u32 oo = rl ? o - 85u : o;
    float th = rl ? t1 : t0;
    bool c = (oo >= 5u) && (v[k] > th);  // lossless pre-filter (thr conservative)
    roll[k] = rl; cand[k] = c; any |= c;
  }
  if (__ballot(any)) {
#pragma unroll
    for (int k = 0; k < 4; ++k) {
      if (cand[k]) {
        u32 R = R0 + (roll[k] ? 1u : 0u);
        float cs = cs_arr[CSB + R];
        float s = cs * sigm(v[k]);   // exact reference expression
        if (s > 0.9f) {
          u32 o = o0 + (u32)k;
          u32 oo = roll[k] ? o - 85u : o;
          u32 b = R / (u32)NREC, r = R - b * (u32)NREC;
          u32 n = (u32)NBT + r;
          int bc = (int)b * NCLS + (int)(oo - 5u);
          int pos = atomicAdd(&cc[bc * CPAD], 1);  // padded: 1 counter / 64B line
          if (pos < CAP)  // high = score bits, low = ~anchor (desc => idx-asc ties)
            ck[(size_t)bc * CAP + pos] =
                ((u64)__float_as_uint(s) << 32) | (0xFFFFFFFFu - n);
        }
      }
    }
  }
}

__global__ __launch_bounds__(256) void scan_kernel(
    const float* __restrict__ p0, const float* __restrict__ p1,
    const float* __restrict__ p2, const float* __restrict__ thr_arr,
    const float* __restrict__ cs_arr,
    u64* __restrict__ cand_keys, int* __restrict__ cand_cnt) {
  u32 base = blockIdx.x * (256u * SCAN_PER) + threadIdx.x;
  f4 v[SCAN_PER];
  u32 t[SCAN_PER];
  int lv[SCAN_PER];
#pragma unroll
  for (int j = 0; j < SCAN_PER; ++j) {  // issue all loads first (8 in flight)
    u32 e4 = base + 256u * j;
    lv[j] = -1;
    if (e4 < NF4_L0) {
      lv[j] = 0; t[j] = e4;
      v[j] = reinterpret_cast<const f4*>(p0)[e4];
    } else if (e4 < NF4_L01) {
      lv[j] = 1; t[j] = e4 - NF4_L0;
      v[j] = reinterpret_cast<const f4*>(p1)[t[j]];
    } else if (e4 < NF4_ALL) {
      lv[j] = 2; t[j] = e4 - NF4_L01;
      v[j] = reinterpret_cast<const f4*>(p2)[t[j]];
    }
  }
#pragma unroll
  for (int j = 0; j < SCAN_PER; ++j) {
    if (lv[j] == 0) scan4<1200, 0, 0>(v[j], t[j] * 4u, thr_arr, cs_arr, cand_keys, cand_cnt);
    else if (lv[j] == 1) scan4<4800, 1200, 19200>(v[j], t[j] * 4u, thr_arr, cs_arr, cand_keys, cand_cnt);
    else if (lv[j] == 2) scan4<19200, 6000, 96000>(v[j], t[j] * 4u, thr_arr, cs_arr, cand_keys, cand_cnt);
  }
}

// ------- Pass 2: histogram-select top-150 + rank + single-wave greedy NMS -------
__global__ __launch_bounds__(256) void nms_kernel(
    const u64* __restrict__ cand_keys, const int* __restrict__ cand_cnt,
    const float* __restrict__ boxes_ws,
    u64* __restrict__ img_keys, int* __restrict__ img_cnt) {
  __shared__ u32 hist[NBINS];
  __shared__ u64 sel[NSEL];     // 8 KB
  __shared__ u64 slot[MAXB];    // top-150 keys by exact rank
  __shared__ float4 sbox[MAXB];
  __shared__ float sarea[MAXB];
  __shared__ int sT, sCge, nsel;
  int bc = blockIdx.x;
  int b = bc / NCLS, c = bc - b * NCLS;
  int tid = threadIdx.x;
  int count = cand_cnt[bc * CPAD];
  if (count > CAP) count = CAP;
  const u64* src = cand_keys + (size_t)bc * CAP;
  for (int i = tid; i < NBINS; i += 256) hist[i] = 0;
  if (tid < MAXB) slot[tid] = 0;
  if (tid == 0) nsel = 0;
  __syncthreads();
  for (int i = tid; i < count; i += 256)
    atomicAdd(&hist[((u32)(src[i] >> 32) - 0x3F666000u) >> 12], 1u);
  __syncthreads();
  if (tid == 0) {
    int target = (count < MAXB) ? count : MAXB;
    int acc = 0, T = 0;
    if (target > 0) {
      for (int j = NBINS - 1; j >= 0; --j) {
        acc += (int)hist[j];
        if (acc >= target) { T = j; break; }
      }
    }
    sT = T;
    sCge = acc;
  }
  __syncthreads();
  int T = sT;
  if (sCge <= NSEL) {
    // compact bins >= T (superset of exact top-target; bin order is key order)
    for (int i = tid; i < count; i += 256) {
      u64 k = src[i];
      if ((int)(((u32)(k >> 32) - 0x3F666000u) >> 12) >= T) {
        int pos = atomicAdd(&nsel, 1);
        sel[pos] = k;
      }
    }
    __syncthreads();
    int C = nsel;
    for (int i = tid; i < C; i += 256) {
      u64 k = sel[i];
      int rank = 0;
      for (int j = 0; j < C; ++j) rank += (sel[j] > k) ? 1 : 0;  // LDS broadcast
      if (rank < MAXB) slot[rank] = k;
    }
  } else {
    // fallback (pathological bin concentration): full exact rank-select
    for (int i = tid; i < count; i += 256) {
      u64 k = src[i];
      int rank = 0;
      for (int j = 0; j < count; ++j) rank += (src[j] > k) ? 1 : 0;
      if (rank < MAXB) slot[rank] = k;
    }
  }
  __syncthreads();
  if (tid < MAXB) {
    u64 k = slot[tid];
    float4 bx = make_float4(0.f, 0.f, 0.f, 0.f);
    if (k) {
      int n = (int)(0xFFFFFFFFu - (u32)(k & 0xFFFFFFFFu));
      bx = reinterpret_cast<const float4*>(boxes_ws)[(size_t)b * NANCH + n];
    }
    sbox[tid] = bx;
    sarea[tid] = (bx.z - bx.x) * (bx.w - bx.y);
  }
  __syncthreads();
  // single-wave greedy NMS: lane owns j in {lane, lane+64, lane+128}; no barriers.
  if (tid < 64) {
    u32 validm = 0, supm = 0;
    float4 myb[3];
    float mya[3];
    for (int s = 0; s < 3; ++s) {
      int j = tid + 64 * s;
      myb[s] = make_float4(0.f, 0.f, 0.f, 0.f);
      mya[s] = 0.f;
      if (j < MAXB && slot[j] != 0) {
        validm |= 1u << s;
        myb[s] = sbox[j];
        mya[s] = sarea[j];
      }
    }
    for (int i = 0; i < MAXB - 1; ++i) {
      int owner = i & 63, si = i >> 6;
      u32 f = __shfl(validm & ~supm, owner);  // keep_i broadcast from owner lane
      if ((f >> si) & 1) {
        float4 bi = sbox[i];
        float ai = sarea[i];
        for (int s = 0; s < 3; ++s) {
          int j = tid + 64 * s;
          if (j > i && j < MAXB && ((validm >> s) & 1) && !((supm >> s) & 1)) {
            float ltx = fmaxf(bi.x, myb[s].x);
            float lty = fmaxf(bi.y, myb[s].y);
            float rbx = fminf(bi.z, myb[s].z);
            float rby = fminf(bi.w, myb[s].w);
            float iw = fmaxf(rbx - ltx, 0.f);
            float ih = fmaxf(rby - lty, 0.f);
            float inter = iw * ih;
            float iou = inter / (ai + mya[s] - inter + 1e-9f);  // ref op order
            if (iou > 0.1f) supm |= 1u << s;
          }
        }
      }
    }
    // wave-aggregated append of kept entries to per-image list
    u32 keepm = validm & ~supm;
    u64 m0 = __ballot(keepm & 1u);
    u64 m1 = __ballot((keepm >> 1) & 1u);
    u64 m2 = __ballot((keepm >> 2) & 1u);
    int total = (int)(__popcll(m0) + __popcll(m1) + __popcll(m2));
    if (total > 0) {
      int base = 0;
      if (tid == 0) base = atomicAdd(&img_cnt[b * CPAD], total);
      base = __shfl(base, 0);
      u64 lt = (1ull << tid) - 1;
      int off0 = (int)__popcll(m0 & lt);
      int off1 = (int)(__popcll(m0) + __popcll(m1 & lt));
      int off2 = (int)(__popcll(m0) + __popcll(m1) + __popcll(m2 & lt));
      for (int s = 0; s < 3; ++s) {
        if ((keepm >> s) & 1) {
          int j = tid + 64 * s;  // j == rank == top_k position
          u64 k = slot[j];
          u32 e = (u32)(c * MAXB + j);
          u32 anchor = (u32)(0xFFFFFFFFu - (u32)(k & 0xFFFFFFFFu));
          int pos = base + ((s == 0) ? off0 : ((s == 1) ? off1 : off2));
          // key = [score:32][(0x3FFF - e):14][anchor:15]  (unique per entry)
          img_keys[(size_t)b * CAP2 + pos] =
              ((k >> 32) << 32) | ((u64)(0x3FFFu - e) << 15) | anchor;
        }
      }
    }
  }
}

// ---------------- Pass 3: per-image top-150 via exact histogram select ----------
__global__ __launch_bounds__(1024) void final_kernel(
    const u64* __restrict__ img_keys, const int* __restrict__ img_cnt,
    const float* __restrict__ boxes_ws, float* __restrict__ out) {
  __shared__ u32 hist[NBINS];
  __shared__ u64 sel[SELCAP];   // 16 KB
  __shared__ u64 slot[MAXB];
  __shared__ int sT, sCge, nsel;
  int b = blockIdx.x, tid = threadIdx.x;
  int L = img_cnt[b * CPAD];
  if (L > CAP2) L = CAP2;
  const u64* src = img_keys + (size_t)b * CAP2;
  for (int i = tid; i < NBINS; i += 1024) hist[i] = 0;
  if (tid < MAXB) slot[tid] = 0;
  if (tid == 0) nsel = 0;
  __syncthreads();
  for (int i = tid; i < L; i += 1024) {
    u32 hi = (u32)(src[i] >> 32);
    atomicAdd(&hist[(hi - 0x3F666000u) >> 12], 1u);
  }
  __syncthreads();
  if (tid == 0) {
    int target = (L < MAXB) ? L : MAXB;
    int acc = 0, T = 0;
    if (target > 0) {
      for (int j = NBINS - 1; j >= 0; --j) {
        acc += (int)hist[j];
        if (acc >= target) { T = j; break; }
      }
    }
    sT = T;
    sCge = acc;
  }
  __syncthreads();
  int T = sT, cge = sCge;
  float* ob = out;                      // [B][150][4]
  float* osc = out + BATCH * MAXB * 4;  // [B][150]
  float* olb = out + BATCH * MAXB * 5;  // [B][150] labels (as float)
  if (cge <= SELCAP) {
    // fast path: compact bins >= T, exact rank-select the small set
    for (int i = tid; i < L; i += 1024) {
      u64 k = src[i];
      if ((int)(((u32)(k >> 32) - 0x3F666000u) >> 12) >= T) {
        int pos = atomicAdd(&nsel, 1);
        sel[pos] = k;
      }
    }
    __syncthreads();
    int C = nsel;
    for (int i = tid; i < C; i += 1024) {
      u64 k = sel[i];
      int rank = 0;
      for (int j = 0; j < C; ++j) rank += (sel[j] > k) ? 1 : 0;  // LDS broadcast
      if (rank < MAXB) slot[rank] = k;
    }
    __syncthreads();
  } else {
    // fallback (pathological concentration): exact rank-select over global list
    for (int i = tid; i < L; i += 1024) {
      u64 k = src[i];
      int rank = 0;
      for (int j = 0; j < L; ++j) rank += (src[j] > k) ? 1 : 0;
      if (rank < MAXB) slot[rank] = k;
    }
    __syncthreads();
  }
  if (tid < MAXB) {
    u64 k = slot[tid];
    float* q = ob + ((size_t)b * MAXB + tid) * 4;
    if (k) {
      u32 e = 0x3FFFu - (u32)((k >> 15) & 0x3FFFu);
      int c = (int)(e / MAXB);
      int anchor = (int)(k & 0x7FFFu);
      float4 bx = reinterpret_cast<const float4*>(boxes_ws)[(size_t)b * NANCH + anchor];
      q[0] = bx.x; q[1] = bx.y; q[2] = bx.z; q[3] = bx.w;
      osc[(size_t)b * MAXB + tid] = __uint_as_float((u32)(k >> 32));
      olb[(size_t)b * MAXB + tid] = (float)c;
    } else {
      q[0] = q[1] = q[2] = q[3] = -1.f;
      osc[(size_t)b * MAXB + tid] = -1.f;
      olb[(size_t)b * MAXB + tid] = -1.f;
    }
  }
}

extern "C" void kernel_launch(void* const* d_in, const int* in_sizes, int n_in,
                              void* d_out, int out_size, void* d_ws, size_t ws_size,
                              hipStream_t stream) {
  (void)in_sizes; (void)n_in; (void)out_size; (void)ws_size;
  const float* p0 = (const float*)d_in[0];  // [16,20,20,255] anchors[6:9]
  const float* p1 = (const float*)d_in[1];  // [16,40,40,255] anchors[3:6]
  const float* p2 = (const float*)d_in[2];  // [16,80,80,255] anchors[0:3]
  char* ws = (char*)d_ws;
  float* boxes_ws = (float*)ws;              // 16*25200*16 B          -> 6,451,200
  int* cand_cnt = (int*)(ws + 6451200);      // 1280*16 i32 (padded)   -> 6,533,120
  int* img_cnt = (int*)(ws + 6533120);       // 16*16 i32 (padded)     -> 6,534,144
  float* cs_arr = (float*)(ws + 6534144);    // 403200+pad f32         -> 8,147,008
  float* thr_arr = (float*)(ws + 8147008);   // 403200+pad f32         -> 9,759,872
  u64* cand_keys = (u64*)(ws + 9759872);     // 1280*2048 u64          -> 30,731,392
  u64* img_keys = (u64*)(ws + 30731392);     // 16*12000 u64           -> 32,267,392

  hipMemsetAsync(cand_cnt, 0, (NCLS * BATCH + BATCH) * CPAD * sizeof(int), stream);

  header_kernel<<<NREC_ALL / 256, 256, 0, stream>>>(p0, p1, p2, boxes_ws,
                                                    cs_arr, thr_arr);
  scan_kernel<<<(NF4_ALL + 256 * SCAN_PER - 1) / (256 * SCAN_PER), 256, 0, stream>>>(
      p0, p1, p2, thr_arr, cs_arr, cand_keys, cand_cnt);
  nms_kernel<<<BATCH * NCLS, 256, 0, stream>>>(cand_keys, cand_cnt, boxes_ws,
                                               img_keys, img_cnt);
  final_kernel<<<BATCH, 1024, 0, stream>>>(img_keys, img_cnt, boxes_ws, (float*)d_out);
}

// Round 10
// 164.322 us; speedup vs baseline: 1.0780x; 1.0780x over previous
//
#include <hip/hip_runtime.h>
#include <stdint.h>

#define NCLS 80
#define MAXB 150
#define BATCH 16
#define NANCH 25200
#define SEGS 4       // candidate-list segments per (image,class) (atomic spread)
#define SEGCAP 512   // per-segment cap; mean fill ~150 -> ~10 sigma margin
#define CAP2 12000   // hard bound: 80 classes * 150 kept max
#define NBINS 411    // score hi-bits (0x3F666666,0x3F800000] -> bins 0..410
#define SELCAP 2048
#define NSEL 1024    // nms histogram-compact capacity (expected ~155)
#define NREC_ALL 403200  // total records across levels/images
#define CPAD 16          // counters padded to one per 64B line (atomic contention fix)

typedef unsigned long long u64;
typedef unsigned int u32;
typedef float f4 __attribute__((ext_vector_type(4)));
typedef f4 f4u __attribute__((aligned(4)));  // 4B-aligned vector load

__device__ __forceinline__ float sigm(float x) { return 1.0f / (1.0f + expf(-x)); }

// ---------------- Pass 1a: headers -> boxes + cs + thr (thread per record) ------
__global__ __launch_bounds__(256) void header_kernel(
    const float* __restrict__ p0, const float* __restrict__ p1,
    const float* __restrict__ p2, float* __restrict__ boxes_ws,
    float* __restrict__ cs_arr, float* __restrict__ thr_arr) {
  int W = blockIdx.x * 256 + threadIdx.x;  // 0..403199, level-major record id
  int lvl, b, r;
  if (W < 19200) { lvl = 0; b = W / 1200; r = W - b * 1200; }
  else if (W < 96000) { int V = W - 19200; lvl = 1; b = V / 4800; r = V - b * 4800; }
  else { int V = W - 96000; lvl = 2; b = V / 19200; r = V - b * 19200; }
  const int gtab[3] = {20, 40, 80};
  const float rtab[3] = {32.f, 16.f, 8.f};
  const int nbt[3] = {0, 1200, 6000};
  const float awt[3][3] = {{116.f, 156.f, 373.f}, {30.f, 62.f, 59.f}, {10.f, 16.f, 33.f}};
  const float aht[3][3] = {{90.f, 198.f, 326.f}, {61.f, 45.f, 119.f}, {13.f, 30.f, 23.f}};
  const float* fm = (lvl == 0) ? p0 : ((lvl == 1) ? p1 : p2);
  int g = gtab[lvl];
  const float* p = fm + ((size_t)b * (g * g * 3) + r) * 85;
  f4 h = *(const f4u*)p;   // tx,ty,tw,th (4B-aligned vector load)
  float tc = p[4];
  int cell = r / 3, a = r - 3 * cell;
  int yy = cell / g, xx = cell - yy * g;
  float ratio = rtab[lvl];
  float cx = (sigm(h.x) + (float)xx) * ratio;
  float cy = (sigm(h.y) + (float)yy) * ratio;
  float w = expf(h.z) * awt[lvl][a];
  float hh = expf(h.w) * aht[lvl][a];
  int n = nbt[lvl] + r;
  reinterpret_cast<float4*>(boxes_ws)[(size_t)b * NANCH + n] = make_float4(
      cx - w * 0.5f, cy - hh * 0.5f, cx + w * 0.5f, cy + hh * 0.5f);
  float cs = sigm(tc);  // score<=cs in fp32 -> cs>0.9 is a lossless gate
  cs_arr[W] = cs;
  // conservative logit threshold: val <= thr  ==>  fl(cs*sigm(val)) <= 0.9f.
  // margin 1e-3 + 4e-7*ratio dominates all fp32 error terms; borderline
  // false-positives are re-tested exactly in class_kernel.
  float thr = __int_as_float(0x7F800000);  // +INF: cs<=0.9 -> no hit possible
  float t = 0.9f / cs;
  if (t < 1.0f) {
    float ratio2 = t / (1.0f - t);
    thr = logf(ratio2) - (1e-3f + 4e-7f * ratio2);
  }
  thr_arr[W] = thr;
}

// ------- Pass 1b: gated class gather (thread per (record, class-float4)) -------
// 81% of records have thr=+INF (cs<=0.9): their class rows are NEVER read.
__global__ __launch_bounds__(256) void class_kernel(
    const float* __restrict__ p0, const float* __restrict__ p1,
    const float* __restrict__ p2, const float* __restrict__ thr_arr,
    const float* __restrict__ cs_arr,
    u64* __restrict__ cand_keys, int* __restrict__ cand_cnt) {
  u32 S = blockIdx.x * 256u + threadIdx.x;  // 0..8,063,999: record*20 + slot
  u32 W = S / 20u, slot = S - W * 20u;      // 20 threads share one record row
  float thr = thr_arr[W];                   // 4B broadcast load gates the row
  if (!(thr < 3e38f)) return;               // cold record: row never touched
  int lvl, b, r;
  const float* fm;
  if (W < 19200u) { lvl = 0; b = W / 1200u; r = W - b * 1200u; fm = p0; }
  else if (W < 96000u) { u32 V = W - 19200u; lvl = 1; b = V / 4800u; r = V - b * 4800u; fm = p1; }
  else { u32 V = W - 96000u; lvl = 2; b = V / 19200u; r = V - b * 19200u; fm = p2; }
  const int lbase[3] = {0, 19200, 96000};
  const int nbt[3] = {0, 1200, 6000};
  const float* p = fm + (size_t)(W - (u32)lbase[lvl]) * 85;
  f4 v = *(const f4u*)(p + 5 + 4 * slot);   // 16B of class logits (4B-aligned)
  u32 n = (u32)nbt[lvl] + (u32)r;
  u32 nkey = 0xFFFFFFFFu - n;
  int seg = blockIdx.x & (SEGS - 1);
#pragma unroll
  for (int k = 0; k < 4; ++k) {
    if (v[k] > thr) {  // lossless pre-filter (thr conservative)
      float cs = cs_arr[W];
      float s = cs * sigm(v[k]);  // exact reference expression
      if (s > 0.9f) {
        int c = 4 * (int)slot + k;
        int bc = b * NCLS + c;
        int pos = atomicAdd(&cand_cnt[(bc * SEGS + seg) * CPAD], 1);
        if (pos < SEGCAP)  // high = score bits, low = ~anchor (desc => idx-asc ties)
          cand_keys[((size_t)bc * SEGS + seg) * SEGCAP + pos] =
              ((u64)__float_as_uint(s) << 32) | nkey;
      }
    }
  }
}

// ------- Pass 2: histogram-select top-150 + rank + single-wave greedy NMS -------
__global__ __launch_bounds__(256) void nms_kernel(
    const u64* __restrict__ cand_keys, const int* __restrict__ cand_cnt,
    const float* __restrict__ boxes_ws,
    u64* __restrict__ img_keys, int* __restrict__ img_cnt) {
  __shared__ u32 hist[NBINS];
  __shared__ u64 sk[SEGS * SEGCAP];  // 16 KB: compact buffer / fallback staging
  __shared__ u64 slot[MAXB];         // top-150 keys by exact rank
  __shared__ float4 sbox[MAXB];
  __shared__ float sarea[MAXB];
  __shared__ int sT, sCge, nsel;
  int bc = blockIdx.x;
  int b = bc / NCLS, c = bc - b * NCLS;
  int tid = threadIdx.x;
  int cnt[SEGS];
  int count = 0;
#pragma unroll
  for (int s = 0; s < SEGS; ++s) {
    int v = cand_cnt[(bc * SEGS + s) * CPAD];
    cnt[s] = (v > SEGCAP) ? SEGCAP : v;
    count += cnt[s];
  }
  const u64* seg_base = cand_keys + (size_t)bc * SEGS * SEGCAP;
  for (int i = tid; i < NBINS; i += 256) hist[i] = 0;
  if (tid < MAXB) slot[tid] = 0;
  if (tid == 0) nsel = 0;
  __syncthreads();
#pragma unroll
  for (int s = 0; s < SEGS; ++s)
    for (int i = tid; i < cnt[s]; i += 256)
      atomicAdd(&hist[((u32)(seg_base[s * SEGCAP + i] >> 32) - 0x3F666000u) >> 12], 1u);
  __syncthreads();
  if (tid == 0) {
    int target = (count < MAXB) ? count : MAXB;
    int acc = 0, T = 0;
    if (target > 0) {
      for (int j = NBINS - 1; j >= 0; --j) {
        acc += (int)hist[j];
        if (acc >= target) { T = j; break; }
      }
    }
    sT = T;
    sCge = acc;
  }
  __syncthreads();
  int T = sT;
  if (sCge <= NSEL) {
    // compact bins >= T (superset of exact top-target; bin order is key order)
#pragma unroll
    for (int s = 0; s < SEGS; ++s)
      for (int i = tid; i < cnt[s]; i += 256) {
        u64 k = seg_base[s * SEGCAP + i];
        if ((int)(((u32)(k >> 32) - 0x3F666000u) >> 12) >= T) {
          int pos = atomicAdd(&nsel, 1);
          sk[pos] = k;
        }
      }
    __syncthreads();
    int C = nsel;
    for (int i = tid; i < C; i += 256) {
      u64 k = sk[i];
      int rank = 0;
      for (int j = 0; j < C; ++j) rank += (sk[j] > k) ? 1 : 0;  // LDS broadcast
      if (rank < MAXB) slot[rank] = k;
    }
  } else {
    // fallback (pathological bin concentration): stage all, full rank-select
    int off = 0;
#pragma unroll
    for (int s = 0; s < SEGS; ++s) {
      for (int i = tid; i < cnt[s]; i += 256) sk[off + i] = seg_base[s * SEGCAP + i];
      off += cnt[s];
    }
    __syncthreads();
    for (int i = tid; i < count; i += 256) {
      u64 k = sk[i];
      int rank = 0;
      for (int j = 0; j < count; ++j) rank += (sk[j] > k) ? 1 : 0;
      if (rank < MAXB) slot[rank] = k;
    }
  }
  __syncthreads();
  if (tid < MAXB) {
    u64 k = slot[tid];
    float4 bx = make_float4(0.f, 0.f, 0.f, 0.f);
    if (k) {
      int n = (int)(0xFFFFFFFFu - (u32)(k & 0xFFFFFFFFu));
      bx = reinterpret_cast<const float4*>(boxes_ws)[(size_t)b * NANCH + n];
    }
    sbox[tid] = bx;
    sarea[tid] = (bx.z - bx.x) * (bx.w - bx.y);
  }
  __syncthreads();
  // single-wave greedy NMS: lane owns j in {lane, lane+64, lane+128}; no barriers.
  if (tid < 64) {
    u32 validm = 0, supm = 0;
    float4 myb[3];
    float mya[3];
    for (int s = 0; s < 3; ++s) {
      int j = tid + 64 * s;
      myb[s] = make_float4(0.f, 0.f, 0.f, 0.f);
      mya[s] = 0.f;
      if (j < MAXB && slot[j] != 0) {
        validm |= 1u << s;
        myb[s] = sbox[j];
        mya[s] = sarea[j];
      }
    }
    for (int i = 0; i < MAXB - 1; ++i) {
      int owner = i & 63, si = i >> 6;
      u32 f = __shfl(validm & ~supm, owner);  // keep_i broadcast from owner lane
      if ((f >> si) & 1) {
        float4 bi = sbox[i];
        float ai = sarea[i];
        for (int s = 0; s < 3; ++s) {
          int j = tid + 64 * s;
          if (j > i && j < MAXB && ((validm >> s) & 1) && !((supm >> s) & 1)) {
            float ltx = fmaxf(bi.x, myb[s].x);
            float lty = fmaxf(bi.y, myb[s].y);
            float rbx = fminf(bi.z, myb[s].z);
            float rby = fminf(bi.w, myb[s].w);
            float iw = fmaxf(rbx - ltx, 0.f);
            float ih = fmaxf(rby - lty, 0.f);
            float inter = iw * ih;
            float iou = inter / (ai + mya[s] - inter + 1e-9f);  // ref op order
            if (iou > 0.1f) supm |= 1u << s;
          }
        }
      }
    }
    // wave-aggregated append of kept entries to per-image list
    u32 keepm = validm & ~supm;
    u64 m0 = __ballot(keepm & 1u);
    u64 m1 = __ballot((keepm >> 1) & 1u);
    u64 m2 = __ballot((keepm >> 2) & 1u);
    int total = (int)(__popcll(m0) + __popcll(m1) + __popcll(m2));
    if (total > 0) {
      int base = 0;
      if (tid == 0) base = atomicAdd(&img_cnt[b * CPAD], total);
      base = __shfl(base, 0);
      u64 lt = (1ull << tid) - 1;
      int off0 = (int)__popcll(m0 & lt);
      int off1 = (int)(__popcll(m0) + __popcll(m1 & lt));
      int off2 = (int)(__popcll(m0) + __popcll(m1) + __popcll(m2 & lt));
      for (int s = 0; s < 3; ++s) {
        if ((keepm >> s) & 1) {
          int j = tid + 64 * s;  // j == rank == top_k position
          u64 k = slot[j];
          u32 e = (u32)(c * MAXB + j);
          u32 anchor = (u32)(0xFFFFFFFFu - (u32)(k & 0xFFFFFFFFu));
          int pos = base + ((s == 0) ? off0 : ((s == 1) ? off1 : off2));
          // key = [score:32][(0x3FFF - e):14][anchor:15]  (unique per entry)
          img_keys[(size_t)b * CAP2 + pos] =
              ((k >> 32) << 32) | ((u64)(0x3FFFu - e) << 15) | anchor;
        }
      }
    }
  }
}

// ---------------- Pass 3: per-image top-150 via exact histogram select ----------
__global__ __launch_bounds__(1024) void final_kernel(
    const u64* __restrict__ img_keys, const int* __restrict__ img_cnt,
    const float* __restrict__ boxes_ws, float* __restrict__ out) {
  __shared__ u32 hist[NBINS];
  __shared__ u64 sel[SELCAP];   // 16 KB
  __shared__ u64 slot[MAXB];
  __shared__ int sT, sCge, nsel;
  int b = blockIdx.x, tid = threadIdx.x;
  int L = img_cnt[b * CPAD];
  if (L > CAP2) L = CAP2;
  const u64* src = img_keys + (size_t)b * CAP2;
  for (int i = tid; i < NBINS; i += 1024) hist[i] = 0;
  if (tid < MAXB) slot[tid] = 0;
  if (tid == 0) nsel = 0;
  __syncthreads();
  for (int i = tid; i < L; i += 1024) {
    u32 hi = (u32)(src[i] >> 32);
    atomicAdd(&hist[(hi - 0x3F666000u) >> 12], 1u);
  }
  __syncthreads();
  if (tid == 0) {
    int target = (L < MAXB) ? L : MAXB;
    int acc = 0, T = 0;
    if (target > 0) {
      for (int j = NBINS - 1; j >= 0; --j) {
        acc += (int)hist[j];
        if (acc >= target) { T = j; break; }
      }
    }
    sT = T;
    sCge = acc;
  }
  __syncthreads();
  int T = sT, cge = sCge;
  float* ob = out;                      // [B][150][4]
  float* osc = out + BATCH * MAXB * 4;  // [B][150]
  float* olb = out + BATCH * MAXB * 5;  // [B][150] labels (as float)
  if (cge <= SELCAP) {
    // fast path: compact bins >= T, exact rank-select the small set
    for (int i = tid; i < L; i += 1024) {
      u64 k = src[i];
      if ((int)(((u32)(k >> 32) - 0x3F666000u) >> 12) >= T) {
        int pos = atomicAdd(&nsel, 1);
        sel[pos] = k;
      }
    }
    __syncthreads();
    int C = nsel;
    for (int i = tid; i < C; i += 1024) {
      u64 k = sel[i];
      int rank = 0;
      for (int j = 0; j < C; ++j) rank += (sel[j] > k) ? 1 : 0;  // LDS broadcast
      if (rank < MAXB) slot[rank] = k;
    }
    __syncthreads();
  } else {
    // fallback (pathological concentration): exact rank-select over global list
    for (int i = tid; i < L; i += 1024) {
      u64 k = src[i];
      int rank = 0;
      for (int j = 0; j < L; ++j) rank += (src[j] > k) ? 1 : 0;
      if (rank < MAXB) slot[rank] = k;
    }
    __syncthreads();
  }
  if (tid < MAXB) {
    u64 k = slot[tid];
    float* q = ob + ((size_t)b * MAXB + tid) * 4;
    if (k) {
      u32 e = 0x3FFFu - (u32)((k >> 15) & 0x3FFFu);
      int c = (int)(e / MAXB);
      int anchor = (int)(k & 0x7FFFu);
      float4 bx = reinterpret_cast<const float4*>(boxes_ws)[(size_t)b * NANCH + anchor];
      q[0] = bx.x; q[1] = bx.y; q[2] = bx.z; q[3] = bx.w;
      osc[(size_t)b * MAXB + tid] = __uint_as_float((u32)(k >> 32));
      olb[(size_t)b * MAXB + tid] = (float)c;
    } else {
      q[0] = q[1] = q[2] = q[3] = -1.f;
      osc[(size_t)b * MAXB + tid] = -1.f;
      olb[(size_t)b * MAXB + tid] = -1.f;
    }
  }
}

extern "C" void kernel_launch(void* const* d_in, const int* in_sizes, int n_in,
                              void* d_out, int out_size, void* d_ws, size_t ws_size,
                              hipStream_t stream) {
  (void)in_sizes; (void)n_in; (void)out_size; (void)ws_size;
  const float* p0 = (const float*)d_in[0];  // [16,20,20,255] anchors[6:9]
  const float* p1 = (const float*)d_in[1];  // [16,40,40,255] anchors[3:6]
  const float* p2 = (const float*)d_in[2];  // [16,80,80,255] anchors[0:3]
  char* ws = (char*)d_ws;
  float* boxes_ws = (float*)ws;              // 16*25200*16 B          -> 6,451,200
  int* cand_cnt = (int*)(ws + 6451200);      // 1280*4*16 i32 (padded) -> 6,778,880
  int* img_cnt = (int*)(ws + 6778880);       // 16*16 i32 (padded)     -> 6,779,904
  float* cs_arr = (float*)(ws + 6779904);    // 403200+pad f32         -> 8,392,720
  float* thr_arr = (float*)(ws + 8392720);   // 403200+pad f32         -> 10,005,536
  u64* cand_keys = (u64*)(ws + 10005536);    // 1280*4*512 u64         -> 30,977,056
  u64* img_keys = (u64*)(ws + 30977056);     // 16*12000 u64           -> 32,513,056

  hipMemsetAsync(cand_cnt, 0, (NCLS * BATCH * SEGS + BATCH) * CPAD * sizeof(int),
                 stream);

  header_kernel<<<NREC_ALL / 256, 256, 0, stream>>>(p0, p1, p2, boxes_ws,
                                                    cs_arr, thr_arr);
  class_kernel<<<NREC_ALL * 20 / 256, 256, 0, stream>>>(
      p0, p1, p2, thr_arr, cs_arr, cand_keys, cand_cnt);
  nms_kernel<<<BATCH * NCLS, 256, 0, stream>>>(cand_keys, cand_cnt, boxes_ws,
                                               img_keys, img_cnt);
  final_kernel<<<BATCH, 1024, 0, stream>>>(img_keys, img_cnt, boxes_ws, (float*)d_out);
}

// Round 11
// 163.693 us; speedup vs baseline: 1.0821x; 1.0038x over previous
//
#include <hip/hip_runtime.h>
#include <stdint.h>

#define NCLS 80
#define MAXB 150
#define BATCH 16
#define NANCH 25200
#define SEGS 4       // candidate-list segments per (image,class) (atomic spread)
#define SEGCAP 512   // per-segment cap; mean fill ~150 -> ~10 sigma margin
#define CAP2 12000   // hard bound: 80 classes * 150 kept max
#define NBINS 411    // score hi-bits (0x3F666666,0x3F800000] -> bins 0..410
#define SELCAP 2048
#define WSEL 256     // nms per-wave compact capacity (expected ~155)
#define NREC_ALL 403200  // total records across levels/images
#define CPAD 16          // counters padded to one per 64B line (atomic contention fix)

typedef unsigned long long u64;
typedef unsigned int u32;
typedef float f4 __attribute__((ext_vector_type(4)));
typedef f4 f4u __attribute__((aligned(4)));  // 4B-aligned vector load

__device__ __forceinline__ float sigm(float x) { return 1.0f / (1.0f + expf(-x)); }

// ---------------- Pass 1a: headers -> boxes + cs + thr (thread per record) ------
__global__ __launch_bounds__(256) void header_kernel(
    const float* __restrict__ p0, const float* __restrict__ p1,
    const float* __restrict__ p2, float* __restrict__ boxes_ws,
    float* __restrict__ cs_arr, float* __restrict__ thr_arr) {
  int W = blockIdx.x * 256 + threadIdx.x;  // 0..403199, level-major record id
  int lvl, b, r;
  if (W < 19200) { lvl = 0; b = W / 1200; r = W - b * 1200; }
  else if (W < 96000) { int V = W - 19200; lvl = 1; b = V / 4800; r = V - b * 4800; }
  else { int V = W - 96000; lvl = 2; b = V / 19200; r = V - b * 19200; }
  const int gtab[3] = {20, 40, 80};
  const float rtab[3] = {32.f, 16.f, 8.f};
  const int nbt[3] = {0, 1200, 6000};
  const float awt[3][3] = {{116.f, 156.f, 373.f}, {30.f, 62.f, 59.f}, {10.f, 16.f, 33.f}};
  const float aht[3][3] = {{90.f, 198.f, 326.f}, {61.f, 45.f, 119.f}, {13.f, 30.f, 23.f}};
  const float* fm = (lvl == 0) ? p0 : ((lvl == 1) ? p1 : p2);
  int g = gtab[lvl];
  const float* p = fm + ((size_t)b * (g * g * 3) + r) * 85;
  f4 h = *(const f4u*)p;   // tx,ty,tw,th (4B-aligned vector load)
  float tc = p[4];
  int cell = r / 3, a = r - 3 * cell;
  int yy = cell / g, xx = cell - yy * g;
  float ratio = rtab[lvl];
  float cx = (sigm(h.x) + (float)xx) * ratio;
  float cy = (sigm(h.y) + (float)yy) * ratio;
  float w = expf(h.z) * awt[lvl][a];
  float hh = expf(h.w) * aht[lvl][a];
  int n = nbt[lvl] + r;
  reinterpret_cast<float4*>(boxes_ws)[(size_t)b * NANCH + n] = make_float4(
      cx - w * 0.5f, cy - hh * 0.5f, cx + w * 0.5f, cy + hh * 0.5f);
  float cs = sigm(tc);  // score<=cs in fp32 -> cs>0.9 is a lossless gate
  cs_arr[W] = cs;
  // conservative logit threshold: val <= thr  ==>  fl(cs*sigm(val)) <= 0.9f.
  // margin 1e-3 + 4e-7*ratio dominates all fp32 error terms; borderline
  // false-positives are re-tested exactly in class_kernel.
  float thr = __int_as_float(0x7F800000);  // +INF: cs<=0.9 -> no hit possible
  float t = 0.9f / cs;
  if (t < 1.0f) {
    float ratio2 = t / (1.0f - t);
    thr = logf(ratio2) - (1e-3f + 4e-7f * ratio2);
  }
  thr_arr[W] = thr;
}

// ------- Pass 1b: gated class gather (thread per (record, class-float4)) -------
// 81% of records have thr=+INF (cs<=0.9): their class rows are NEVER read.
__global__ __launch_bounds__(256) void class_kernel(
    const float* __restrict__ p0, const float* __restrict__ p1,
    const float* __restrict__ p2, const float* __restrict__ thr_arr,
    const float* __restrict__ cs_arr,
    u64* __restrict__ cand_keys, int* __restrict__ cand_cnt) {
  u32 S = blockIdx.x * 256u + threadIdx.x;  // 0..8,063,999: record*20 + slot
  u32 W = S / 20u, slot = S - W * 20u;      // 20 threads share one record row
  float thr = thr_arr[W];                   // 4B broadcast load gates the row
  if (!(thr < 3e38f)) return;               // cold record: row never touched
  int lvl, b, r;
  const float* fm;
  if (W < 19200u) { lvl = 0; b = W / 1200u; r = W - b * 1200u; fm = p0; }
  else if (W < 96000u) { u32 V = W - 19200u; lvl = 1; b = V / 4800u; r = V - b * 4800u; fm = p1; }
  else { u32 V = W - 96000u; lvl = 2; b = V / 19200u; r = V - b * 19200u; fm = p2; }
  const int lbase[3] = {0, 19200, 96000};
  const int nbt[3] = {0, 1200, 6000};
  const float* p = fm + (size_t)(W - (u32)lbase[lvl]) * 85;
  f4 v = *(const f4u*)(p + 5 + 4 * slot);   // 16B of class logits (4B-aligned)
  u32 n = (u32)nbt[lvl] + (u32)r;
  u32 nkey = 0xFFFFFFFFu - n;
  int seg = blockIdx.x & (SEGS - 1);
#pragma unroll
  for (int k = 0; k < 4; ++k) {
    if (v[k] > thr) {  // lossless pre-filter (thr conservative)
      float cs = cs_arr[W];
      float s = cs * sigm(v[k]);  // exact reference expression
      if (s > 0.9f) {
        int c = 4 * (int)slot + k;
        int bc = b * NCLS + c;
        int pos = atomicAdd(&cand_cnt[(bc * SEGS + seg) * CPAD], 1);
        if (pos < SEGCAP)  // high = score bits, low = ~anchor (desc => idx-asc ties)
          cand_keys[((size_t)bc * SEGS + seg) * SEGCAP + pos] =
              ((u64)__float_as_uint(s) << 32) | nkey;
      }
    }
  }
}

// ------- Pass 2: one WAVE per (image,class): hist-select + rank + greedy NMS ----
// 64-thread blocks, zero __syncthreads: same-wave DS ordering + ballot/shfl only.
__global__ __launch_bounds__(64) void nms_kernel(
    const u64* __restrict__ cand_keys, const int* __restrict__ cand_cnt,
    const float* __restrict__ boxes_ws,
    u64* __restrict__ img_keys, int* __restrict__ img_cnt) {
  __shared__ u32 hist[NBINS];    // 1644 B
  __shared__ u64 sel[WSEL];      // 2048 B
  __shared__ u64 slot[MAXB];     // 1200 B
  __shared__ float4 sbox[MAXB];  // 2400 B
  __shared__ float sarea[MAXB];  // 600 B
  int bc = blockIdx.x;
  int b = bc / NCLS, c = bc - b * NCLS;
  int lane = threadIdx.x;
  u64 ltm = (1ull << lane) - 1;
  int cnt[SEGS];
  int count = 0;
#pragma unroll
  for (int s = 0; s < SEGS; ++s) {
    int v = cand_cnt[(bc * SEGS + s) * CPAD];
    cnt[s] = (v > SEGCAP) ? SEGCAP : v;
    count += cnt[s];
  }
  const u64* seg_base = cand_keys + (size_t)bc * SEGS * SEGCAP;
  for (int i = lane; i < NBINS; i += 64) hist[i] = 0;
  for (int i = lane; i < MAXB; i += 64) slot[i] = 0;
  // histogram of score hi-bits (in-wave LDS atomics; same-wave order guaranteed)
#pragma unroll
  for (int s = 0; s < SEGS; ++s)
    for (int i = lane; i - lane < cnt[s]; i += 64)
      if (i < cnt[s])
        atomicAdd(&hist[((u32)(seg_base[s * SEGCAP + i] >> 32) - 0x3F666000u) >> 12], 1u);
  // wave-parallel suffix-scan threshold: lane owns 7-bin chunk
  int target = (count < MAXB) ? count : MAXB;
  u32 bsum[7];
  u32 csum = 0;
  int chunk = lane * 7;  // 64*7 = 448 >= NBINS
#pragma unroll
  for (int m = 0; m < 7; ++m) {
    int j = chunk + m;
    u32 hv = (j < NBINS) ? hist[j] : 0u;
    bsum[m] = hv;
    csum += hv;
  }
  u32 S = csum;  // inclusive suffix sum over lanes: S_l = chunks l..63
#pragma unroll
  for (int off = 1; off < 64; off <<= 1) {
    u32 o = __shfl_down(S, off);
    if (lane + off < 64) S += o;
  }
  u32 Snext = S - csum;
  bool win = (S >= (u32)target) && (Snext < (u32)target);  // unique lane (target>=1)
  u64 wmask = __ballot(win);
  int T = NBINS;
  u32 Cge = 0;
  if (wmask) {
    int Tc = 0;
    u32 Cc = 0;
    if (win) {  // largest bin index in my chunk with suffix >= target
      u32 acc = Snext;
#pragma unroll
      for (int m = 6; m >= 0; --m) {
        acc += bsum[m];
        if (acc >= (u32)target) { Tc = chunk + m; Cc = acc; break; }
      }
    }
    int wl = __ffsll(wmask) - 1;
    T = __shfl(Tc, wl);
    Cge = __shfl(Cc, wl);
  }
  if (Cge <= WSEL) {
    // compact bins >= T via ballot offsets (no atomics); C == Cge
    int C = 0;
#pragma unroll
    for (int s = 0; s < SEGS; ++s)
      for (int i = lane; i - lane < cnt[s]; i += 64) {
        bool in = false;
        u64 k = 0;
        if (i < cnt[s]) {
          k = seg_base[s * SEGCAP + i];
          in = (int)(((u32)(k >> 32) - 0x3F666000u) >> 12) >= T;
        }
        u64 m = __ballot(in);
        if (in) sel[C + (int)__popcll(m & ltm)] = k;
        C += (int)__popcll(m);
      }
    // exact rank-select of the small set (keys unique; sel[j] is LDS broadcast)
    for (int i = lane; i < C; i += 64) {
      u64 k = sel[i];
      int rank = 0;
      for (int j = 0; j < C; ++j) rank += (sel[j] > k) ? 1 : 0;
      if (rank < MAXB) slot[rank] = k;
    }
  } else {
    // fallback (pathological bin concentration; never taken on this data)
#pragma unroll
    for (int s = 0; s < SEGS; ++s)
      for (int i = lane; i - lane < cnt[s]; i += 64)
        if (i < cnt[s]) {
          u64 k = seg_base[s * SEGCAP + i];
          int rank = 0;
          for (int s2 = 0; s2 < SEGS; ++s2)
            for (int j = 0; j < cnt[s2]; ++j)
              rank += (seg_base[s2 * SEGCAP + j] > k) ? 1 : 0;
          if (rank < MAXB) slot[rank] = k;
        }
  }
  // box gather for the top-150
  for (int j = lane; j < MAXB; j += 64) {
    u64 k = slot[j];
    float4 bx = make_float4(0.f, 0.f, 0.f, 0.f);
    if (k) {
      int n = (int)(0xFFFFFFFFu - (u32)(k & 0xFFFFFFFFu));
      bx = reinterpret_cast<const float4*>(boxes_ws)[(size_t)b * NANCH + n];
    }
    sbox[j] = bx;
    sarea[j] = (bx.z - bx.x) * (bx.w - bx.y);
  }
  // single-wave greedy NMS: lane owns j in {lane, lane+64, lane+128}
  u32 validm = 0, supm = 0;
  float4 myb[3];
  float mya[3];
#pragma unroll
  for (int s = 0; s < 3; ++s) {
    int j = lane + 64 * s;
    myb[s] = make_float4(0.f, 0.f, 0.f, 0.f);
    mya[s] = 0.f;
    if (j < MAXB && slot[j] != 0) {
      validm |= 1u << s;
      myb[s] = sbox[j];
      mya[s] = sarea[j];
    }
  }
  for (int i = 0; i < MAXB - 1; ++i) {
    int owner = i & 63, si = i >> 6;
    u32 f = __shfl(validm & ~supm, owner);  // keep_i broadcast from owner lane
    if ((f >> si) & 1) {
      float4 bi = sbox[i];
      float ai = sarea[i];
#pragma unroll
      for (int s = 0; s < 3; ++s) {
        int j = lane + 64 * s;
        if (j > i && j < MAXB && ((validm >> s) & 1) && !((supm >> s) & 1)) {
          float ltx = fmaxf(bi.x, myb[s].x);
          float lty = fmaxf(bi.y, myb[s].y);
          float rbx = fminf(bi.z, myb[s].z);
          float rby = fminf(bi.w, myb[s].w);
          float iw = fmaxf(rbx - ltx, 0.f);
          float ih = fmaxf(rby - lty, 0.f);
          float inter = iw * ih;
          float iou = inter / (ai + mya[s] - inter + 1e-9f);  // ref op order
          if (iou > 0.1f) supm |= 1u << s;
        }
      }
    }
  }
  // wave-aggregated append of kept entries to per-image list
  u32 keepm = validm & ~supm;
  u64 m0 = __ballot(keepm & 1u);
  u64 m1 = __ballot((keepm >> 1) & 1u);
  u64 m2 = __ballot((keepm >> 2) & 1u);
  int total = (int)(__popcll(m0) + __popcll(m1) + __popcll(m2));
  if (total > 0) {
    int base = 0;
    if (lane == 0) base = atomicAdd(&img_cnt[b * CPAD], total);
    base = __shfl(base, 0);
    int off0 = (int)__popcll(m0 & ltm);
    int off1 = (int)(__popcll(m0) + __popcll(m1 & ltm));
    int off2 = (int)(__popcll(m0) + __popcll(m1) + __popcll(m2 & ltm));
#pragma unroll
    for (int s = 0; s < 3; ++s) {
      if ((keepm >> s) & 1) {
        int j = lane + 64 * s;  // j == rank == top_k position
        u64 k = slot[j];
        u32 e = (u32)(c * MAXB + j);
        u32 anchor = (u32)(0xFFFFFFFFu - (u32)(k & 0xFFFFFFFFu));
        int pos = base + ((s == 0) ? off0 : ((s == 1) ? off1 : off2));
        // key = [score:32][(0x3FFF - e):14][anchor:15]  (unique per entry)
        img_keys[(size_t)b * CAP2 + pos] =
            ((k >> 32) << 32) | ((u64)(0x3FFFu - e) << 15) | anchor;
      }
    }
  }
}

// ---------------- Pass 3: per-image top-150 via exact histogram select ----------
__global__ __launch_bounds__(1024) void final_kernel(
    const u64* __restrict__ img_keys, const int* __restrict__ img_cnt,
    const float* __restrict__ boxes_ws, float* __restrict__ out) {
  __shared__ u32 hist[NBINS];
  __shared__ u64 sel[SELCAP];   // 16 KB
  __shared__ u64 slot[MAXB];
  __shared__ int sT, sCge, nsel;
  int b = blockIdx.x, tid = threadIdx.x;
  int L = img_cnt[b * CPAD];
  if (L > CAP2) L = CAP2;
  const u64* src = img_keys + (size_t)b * CAP2;
  for (int i = tid; i < NBINS; i += 1024) hist[i] = 0;
  if (tid < MAXB) slot[tid] = 0;
  if (tid == 0) nsel = 0;
  __syncthreads();
  for (int i = tid; i < L; i += 1024) {
    u32 hi = (u32)(src[i] >> 32);
    atomicAdd(&hist[(hi - 0x3F666000u) >> 12], 1u);
  }
  __syncthreads();
  if (tid < 64) {  // wave-parallel suffix-scan threshold (replaces serial 411-loop)
    int lane = tid;
    int target = (L < MAXB) ? L : MAXB;
    u32 bsum[7];
    u32 csum = 0;
    int chunk = lane * 7;
#pragma unroll
    for (int m = 0; m < 7; ++m) {
      int j = chunk + m;
      u32 hv = (j < NBINS) ? hist[j] : 0u;
      bsum[m] = hv;
      csum += hv;
    }
    u32 S = csum;
#pragma unroll
    for (int off = 1; off < 64; off <<= 1) {
      u32 o = __shfl_down(S, off);
      if (lane + off < 64) S += o;
    }
    u32 Snext = S - csum;
    bool win = (S >= (u32)target) && (Snext < (u32)target);
    u64 wmask = __ballot(win);
    int T = NBINS;
    u32 Cge = 0;
    if (wmask) {
      int Tc = 0;
      u32 Cc = 0;
      if (win) {
        u32 acc = Snext;
#pragma unroll
        for (int m = 6; m >= 0; --m) {
          acc += bsum[m];
          if (acc >= (u32)target) { Tc = chunk + m; Cc = acc; break; }
        }
      }
      int wl = __ffsll(wmask) - 1;
      T = __shfl(Tc, wl);
      Cge = __shfl(Cc, wl);
    }
    if (lane == 0) { sT = T; sCge = (int)Cge; }
  }
  __syncthreads();
  int T = sT, cge = sCge;
  float* ob = out;                      // [B][150][4]
  float* osc = out + BATCH * MAXB * 4;  // [B][150]
  float* olb = out + BATCH * MAXB * 5;  // [B][150] labels (as float)
  if (cge <= SELCAP) {
    // fast path: compact bins >= T, exact rank-select the small set
    for (int i = tid; i < L; i += 1024) {
      u64 k = src[i];
      if ((int)(((u32)(k >> 32) - 0x3F666000u) >> 12) >= T) {
        int pos = atomicAdd(&nsel, 1);
        sel[pos] = k;
      }
    }
    __syncthreads();
    int C = nsel;
    for (int i = tid; i < C; i += 1024) {
      u64 k = sel[i];
      int rank = 0;
      for (int j = 0; j < C; ++j) rank += (sel[j] > k) ? 1 : 0;  // LDS broadcast
      if (rank < MAXB) slot[rank] = k;
    }
    __syncthreads();
  } else {
    // fallback (pathological concentration): exact rank-select over global list
    for (int i = tid; i < L; i += 1024) {
      u64 k = src[i];
      int rank = 0;
      for (int j = 0; j < L; ++j) rank += (src[j] > k) ? 1 : 0;
      if (rank < MAXB) slot[rank] = k;
    }
    __syncthreads();
  }
  if (tid < MAXB) {
    u64 k = slot[tid];
    float* q = ob + ((size_t)b * MAXB + tid) * 4;
    if (k) {
      u32 e = 0x3FFFu - (u32)((k >> 15) & 0x3FFFu);
      int c = (int)(e / MAXB);
      int anchor = (int)(k & 0x7FFFu);
      float4 bx = reinterpret_cast<const float4*>(boxes_ws)[(size_t)b * NANCH + anchor];
      q[0] = bx.x; q[1] = bx.y; q[2] = bx.z; q[3] = bx.w;
      osc[(size_t)b * MAXB + tid] = __uint_as_float((u32)(k >> 32));
      olb[(size_t)b * MAXB + tid] = (float)c;
    } else {
      q[0] = q[1] = q[2] = q[3] = -1.f;
      osc[(size_t)b * MAXB + tid] = -1.f;
      olb[(size_t)b * MAXB + tid] = -1.f;
    }
  }
}

extern "C" void kernel_launch(void* const* d_in, const int* in_sizes, int n_in,
                              void* d_out, int out_size, void* d_ws, size_t ws_size,
                              hipStream_t stream) {
  (void)in_sizes; (void)n_in; (void)out_size; (void)ws_size;
  const float* p0 = (const float*)d_in[0];  // [16,20,20,255] anchors[6:9]
  const float* p1 = (const float*)d_in[1];  // [16,40,40,255] anchors[3:6]
  const float* p2 = (const float*)d_in[2];  // [16,80,80,255] anchors[0:3]
  char* ws = (char*)d_ws;
  float* boxes_ws = (float*)ws;              // 16*25200*16 B          -> 6,451,200
  int* cand_cnt = (int*)(ws + 6451200);      // 1280*4*16 i32 (padded) -> 6,778,880
  int* img_cnt = (int*)(ws + 6778880);       // 16*16 i32 (padded)     -> 6,779,904
  float* cs_arr = (float*)(ws + 6779904);    // 403200+pad f32         -> 8,392,720
  float* thr_arr = (float*)(ws + 8392720);   // 403200+pad f32         -> 10,005,536
  u64* cand_keys = (u64*)(ws + 10005536);    // 1280*4*512 u64         -> 30,977,056
  u64* img_keys = (u64*)(ws + 30977056);     // 16*12000 u64           -> 32,513,056

  hipMemsetAsync(cand_cnt, 0, (NCLS * BATCH * SEGS + BATCH) * CPAD * sizeof(int),
                 stream);

  header_kernel<<<NREC_ALL / 256, 256, 0, stream>>>(p0, p1, p2, boxes_ws,
                                                    cs_arr, thr_arr);
  class_kernel<<<NREC_ALL * 20 / 256, 256, 0, stream>>>(
      p0, p1, p2, thr_arr, cs_arr, cand_keys, cand_cnt);
  nms_kernel<<<BATCH * NCLS, 64, 0, stream>>>(cand_keys, cand_cnt, boxes_ws,
                                              img_keys, img_cnt);
  final_kernel<<<BATCH, 1024, 0, stream>>>(img_keys, img_cnt, boxes_ws, (float*)d_out);
}